// Round 1
// baseline (4774.934 us; speedup 1.0000x reference)
//
#include <hip/hip_runtime.h>

#define VV 32000
#define EE 512
#define HH 1024
#define NB 64
#define NSTEP 32

typedef __attribute__((ext_vector_type(8))) short short8;
typedef __attribute__((ext_vector_type(4))) float f32x4;

__device__ __forceinline__ unsigned short f2bf(float f) {
  unsigned int u = __float_as_uint(f);
  u += 0x7fffu + ((u >> 16) & 1u);
  return (unsigned short)(u >> 16);
}
__device__ __forceinline__ float dot4(float4 a, float4 b) {
  return a.x * b.x + a.y * b.y + a.z * b.z + a.w * b.w;
}
__device__ __forceinline__ float sigmoidf_(float x) { return 1.0f / (1.0f + expf(-x)); }

// ---------------- prep: fc_W fp32 -> bf16 fragment-swizzled layout ----------------
// Wfrag[vt][kstep][lane][8] bf16; vt=v/16 (2000), kstep=k/32 (32), lane: v%16 + 16*((k%32)/8)
__global__ __launch_bounds__(256) void prep_w(const float* __restrict__ fcW,
                                              unsigned short* __restrict__ wfrag) {
  int vt = blockIdx.x;  // 0..1999
  int v0 = vt << 4;
  for (int i = threadIdx.x; i < 16384; i += 256) {
    int kstep = i >> 9;
    int rem = i & 511;
    int lane = rem >> 3;
    int j = rem & 7;
    int v = v0 + (lane & 15);
    int k = (kstep << 5) + ((lane >> 4) << 3) + j;
    wfrag[(size_t)vt * 16384 + i] = f2bf(fcW[(size_t)v * HH + k]);
  }
}

// ---------------- init: h0 from encoder_hidden, x0 = emb[SOS] ----------------
// h4 layout: [kq=H/4][b][4] fp32 ; x4 layout: [kq=E/4][b][4] fp32
__global__ __launch_bounds__(256) void init_kernel(const float* __restrict__ enc,
                                                   const float* __restrict__ emb,
                                                   float* __restrict__ h4,
                                                   float* __restrict__ x4) {
  int i = blockIdx.x * 256 + threadIdx.x;  // 65536 threads
  int b = i >> 10, u = i & 1023;
  h4[(((u >> 2) * NB + b) << 2) + (u & 3)] = enc[b * HH + u];
  if (i < NB * EE) {
    int b2 = i >> 9, k = i & 511;
    x4[(((k >> 2) * NB + b2) << 2) + (k & 3)] = emb[EE + k];  // SOS token = 1
  }
}

// ---------------- GRU step (fp32) ----------------
// 256 blocks x 256 thr; wave <-> u (1024 total), lane <-> b.
// Writes h4out (fp32) and afrag (bf16 MFMA-A fragment layout of h_new).
__global__ __launch_bounds__(256) void gru_kernel(
    const float* __restrict__ x4, const float* __restrict__ h4in, float* __restrict__ h4out,
    const float* __restrict__ Wih, const float* __restrict__ Whh,
    const float* __restrict__ bih, const float* __restrict__ bhh,
    unsigned short* __restrict__ afrag) {
  __shared__ float4 tile[32 * 64];  // 32 kq x 64 b, 32 KiB
  const int tid = threadIdx.x;
  const int lane = tid & 63;
  const int su = __builtin_amdgcn_readfirstlane(blockIdx.x * 4 + (tid >> 6));

  float air = 0.f, aiz = 0.f, ain = 0.f, ahr = 0.f, ahz = 0.f, ahn = 0.f;
  const float4* x4v = (const float4*)x4;   // [128][64]
  const float4* h4v = (const float4*)h4in; // [256][64]

  // x part: K=512 -> 4 chunks of 32 kq
  for (int c = 0; c < 4; ++c) {
    __syncthreads();
    for (int i = tid; i < 2048; i += 256) tile[i] = x4v[c * 2048 + i];
    __syncthreads();
    const float* wr = Wih + (size_t)su * EE + c * 128;
    const float* wz = Wih + (size_t)(HH + su) * EE + c * 128;
    const float* wn = Wih + (size_t)(2 * HH + su) * EE + c * 128;
    for (int q = 0; q < 32; ++q) {
      float4 xv = tile[q * 64 + lane];
      float4 w0 = *(const float4*)(wr + q * 4);
      float4 w1 = *(const float4*)(wz + q * 4);
      float4 w2 = *(const float4*)(wn + q * 4);
      air += dot4(xv, w0);
      aiz += dot4(xv, w1);
      ain += dot4(xv, w2);
    }
  }
  // h part: K=1024 -> 8 chunks of 32 kq
  for (int c = 0; c < 8; ++c) {
    __syncthreads();
    for (int i = tid; i < 2048; i += 256) tile[i] = h4v[c * 2048 + i];
    __syncthreads();
    const float* wr = Whh + (size_t)su * HH + c * 128;
    const float* wz = Whh + (size_t)(HH + su) * HH + c * 128;
    const float* wn = Whh + (size_t)(2 * HH + su) * HH + c * 128;
    for (int q = 0; q < 32; ++q) {
      float4 hv = tile[q * 64 + lane];
      float4 w0 = *(const float4*)(wr + q * 4);
      float4 w1 = *(const float4*)(wz + q * 4);
      float4 w2 = *(const float4*)(wn + q * 4);
      ahr += dot4(hv, w0);
      ahz += dot4(hv, w1);
      ahn += dot4(hv, w2);
    }
  }

  float hold = h4in[(((su >> 2) * NB + lane) << 2) + (su & 3)];
  float r = sigmoidf_((air + bih[su]) + (ahr + bhh[su]));
  float z = sigmoidf_((aiz + bih[HH + su]) + (ahz + bhh[HH + su]));
  float n = tanhf((ain + bih[2 * HH + su]) + r * (ahn + bhh[2 * HH + su]));
  float hn = (1.0f - z) * n + z * hold;

  h4out[(((su >> 2) * NB + lane) << 2) + (su & 3)] = hn;
  // A-fragment layout: [mtile=b/16][kstep=u/32][lane=(b%16)+16*((u%32)/8)][j=u%8]
  int lp = (lane & 15) + (((su >> 3) & 3) << 4);
  afrag[((((lane >> 4) * 32 + (su >> 5)) * 64 + lp) << 3) + (su & 7)] = f2bf(hn);
}

// ---------------- FC: logits = h @ fc_W^T  (bf16 MFMA, K-split halves) ----------------
// grid 1000 x 64thr: block -> (vgroup = bi>>1 of 64 v, khalf = bi&1 of K=512)
__global__ __launch_bounds__(64) void fc_kernel(const unsigned short* __restrict__ afrag,
                                                const unsigned short* __restrict__ wfrag,
                                                float* __restrict__ l0,
                                                float* __restrict__ l1) {
  const int lane = threadIdx.x;
  const int vg = blockIdx.x >> 1;
  const int kh = blockIdx.x & 1;
  float* lout = kh ? l1 : l0;

  f32x4 acc[4][4] = {};
  const short8* A = (const short8*)afrag;   // [(m*32+kstep)*64 + lane]
  const short8* Bw = (const short8*)wfrag;  // [(vt*32+kstep)*64 + lane]
  const int ks0 = kh * 16;

  for (int s = 0; s < 16; ++s) {
    int kstep = ks0 + s;
    short8 av[4], bv[4];
#pragma unroll
    for (int m = 0; m < 4; ++m) av[m] = A[(m * 32 + kstep) * 64 + lane];
#pragma unroll
    for (int n = 0; n < 4; ++n) bv[n] = Bw[((vg * 4 + n) * 32 + kstep) * 64 + lane];
#pragma unroll
    for (int n = 0; n < 4; ++n)
#pragma unroll
      for (int m = 0; m < 4; ++m)
        acc[m][n] = __builtin_amdgcn_mfma_f32_16x16x32_bf16(av[m], bv[n], acc[m][n], 0, 0, 0);
  }

  // C/D layout: col = lane&15 (v), row = (lane>>4)*4 + reg (b)
  const int r0 = (lane >> 4) << 2;
  const int c0 = lane & 15;
#pragma unroll
  for (int m = 0; m < 4; ++m)
#pragma unroll
    for (int n = 0; n < 4; ++n)
#pragma unroll
      for (int reg = 0; reg < 4; ++reg) {
        int b = m * 16 + r0 + reg;
        int v = vg * 64 + n * 16 + c0;
        lout[b * VV + v] = acc[m][n][reg];
      }
}

// ---------------- reduce: log-softmax + exact-refined argmax + embed next token ------
__global__ __launch_bounds__(1024) void reduce_kernel(
    const float* __restrict__ l0, const float* __restrict__ l1, const float* __restrict__ fcb,
    const float* __restrict__ emb, const float* __restrict__ fcW, const float* __restrict__ h4,
    float* __restrict__ x4, float* __restrict__ out, int t) {
  const int b = blockIdx.x;
  const int tid = threadIdx.x;
  __shared__ float mred[1024], sred[1024];
  __shared__ int cnt;
  __shared__ int cand[64];
  __shared__ float cex[64];
  __shared__ int stok;

  // Phase A: online max/sum of approx logits
  float m = -INFINITY, s = 0.f;
  for (int v = tid; v < VV; v += 1024) {
    float x = (l0[b * VV + v] + l1[b * VV + v]) + fcb[v];
    if (x > m) {
      s = s * expf(m - x) + 1.0f;
      m = x;
    } else {
      s += expf(x - m);
    }
  }
  mred[tid] = m;
  sred[tid] = s;
  __syncthreads();
  for (int off = 512; off > 0; off >>= 1) {
    if (tid < off) {
      float m1 = mred[tid], s1 = sred[tid];
      float m2 = mred[tid + off], s2 = sred[tid + off];
      float M = fmaxf(m1, m2);
      mred[tid] = M;
      sred[tid] = s1 * expf(m1 - M) + s2 * expf(m2 - M);
    }
    __syncthreads();
  }
  if (tid == 0) cnt = 0;
  const float mtot = mred[0];
  const float lse = mtot + logf(sred[0]);
  __syncthreads();

  // Phase B: write logp, collect near-max candidates
  for (int v = tid; v < VV; v += 1024) {
    float x = (l0[b * VV + v] + l1[b * VV + v]) + fcb[v];
    out[(size_t)b * (NSTEP * (size_t)VV) + (size_t)t * VV + v] = x - lse;
    if (x >= mtot - 0.0625f) {
      int p = atomicAdd(&cnt, 1);
      if (p < 64) cand[p] = v;
    }
  }
  __syncthreads();
  int nc = cnt < 64 ? cnt : 64;

  // Phase C: exact fp32 recompute of candidate logits (one wave per candidate)
  const int wv = tid >> 6, ln = tid & 63;
  for (int ci = wv; ci < nc; ci += 16) {
    int c = cand[ci];
    float p = 0.f;
#pragma unroll
    for (int i = 0; i < 16; ++i) {
      int k = ln + (i << 6);
      p += h4[(((k >> 2) * NB + b) << 2) + (k & 3)] * fcW[(size_t)c * HH + k];
    }
    for (int d = 1; d < 64; d <<= 1) p += __shfl_xor(p, d);
    if (ln == 0) cex[ci] = p + fcb[c];
  }
  __syncthreads();
  if (tid == 0) {
    float best = -INFINITY;
    int bi_ = 0x7fffffff;
    for (int ci = 0; ci < nc; ++ci) {
      float e = cex[ci];
      int v = cand[ci];
      if (e > best || (e == best && v < bi_)) {
        best = e;
        bi_ = v;
      }
    }
    stok = bi_;
  }
  __syncthreads();

  // Phase D: embed next token into x4
  const int tok = stok;
  for (int k = tid; k < EE; k += 1024) {
    x4[(((k >> 2) * NB + b) << 2) + (k & 3)] = emb[(size_t)tok * EE + k];
  }
}

// ---------------- final: write hT tail of output ----------------
__global__ __launch_bounds__(256) void final_kernel(const float* __restrict__ h4,
                                                    float* __restrict__ out) {
  int i = blockIdx.x * 256 + threadIdx.x;  // 65536
  int b = i >> 10, u = i & 1023;
  out[(size_t)NB * NSTEP * VV + i] = h4[(((u >> 2) * NB + b) << 2) + (u & 3)];
}

extern "C" void kernel_launch(void* const* d_in, const int* in_sizes, int n_in,
                              void* d_out, int out_size, void* d_ws, size_t ws_size,
                              hipStream_t stream) {
  const float* enc = (const float*)d_in[1];
  const float* emb = (const float*)d_in[2];
  const float* Wih = (const float*)d_in[3];
  const float* Whh = (const float*)d_in[4];
  const float* bih = (const float*)d_in[5];
  const float* bhh = (const float*)d_in[6];
  const float* fcW = (const float*)d_in[7];
  const float* fcb = (const float*)d_in[8];
  float* out = (float*)d_out;

  char* ws = (char*)d_ws;
  unsigned short* wfrag = (unsigned short*)ws; ws += (size_t)2000 * 16384 * 2;  // 65,536,000
  unsigned short* afrag = (unsigned short*)ws; ws += (size_t)4 * 32 * 64 * 8 * 2;  // 131,072
  float* h4a = (float*)ws; ws += (size_t)NB * HH * 4;   // 262,144
  float* h4b = (float*)ws; ws += (size_t)NB * HH * 4;   // 262,144
  float* x4  = (float*)ws; ws += (size_t)NB * EE * 4;   // 131,072
  float* l0  = (float*)ws; ws += (size_t)NB * VV * 4;   // 8,192,000
  float* l1  = (float*)ws; ws += (size_t)NB * VV * 4;   // 8,192,000

  prep_w<<<2000, 256, 0, stream>>>(fcW, wfrag);
  init_kernel<<<256, 256, 0, stream>>>(enc, emb, h4a, x4);

  for (int t = 0; t < NSTEP; ++t) {
    float* hin = (t & 1) ? h4b : h4a;
    float* hout = (t & 1) ? h4a : h4b;
    gru_kernel<<<256, 256, 0, stream>>>(x4, hin, hout, Wih, Whh, bih, bhh, afrag);
    fc_kernel<<<1000, 64, 0, stream>>>(afrag, wfrag, l0, l1);
    reduce_kernel<<<64, 1024, 0, stream>>>(l0, l1, fcb, emb, fcW, hout, x4, out, t);
  }
  final_kernel<<<256, 256, 0, stream>>>(h4a, out);  // t=31 wrote h4a
}

// Round 2
// 4692.430 us; speedup vs baseline: 1.0176x; 1.0176x over previous
//
#include <hip/hip_runtime.h>

#define VV 32000
#define EE 512
#define HH 1024
#define NB 64
#define NSTEP 32
#define GKSTRIDE 512  // ull units -> slots 4 KiB apart (spread atomics across channels)

typedef __attribute__((ext_vector_type(8))) short short8;
typedef __attribute__((ext_vector_type(4))) float f32x4;

__device__ __forceinline__ unsigned short f2bf(float f) {
  unsigned int u = __float_as_uint(f);
  u += 0x7fffu + ((u >> 16) & 1u);
  return (unsigned short)(u >> 16);
}
__device__ __forceinline__ float bf2f(unsigned short b) {
  return __uint_as_float(((unsigned int)b) << 16);
}
__device__ __forceinline__ float dot4(float4 a, float4 b) {
  return a.x * b.x + a.y * b.y + a.z * b.z + a.w * b.w;
}
__device__ __forceinline__ float sigmoidf_(float x) { return 1.0f / (1.0f + expf(-x)); }
__device__ __forceinline__ unsigned int ordkey(float f) {
  unsigned int u = __float_as_uint(f);
  return u ^ ((u >> 31) ? 0xFFFFFFFFu : 0x80000000u);
}

// ---------- prep: fcW fp32 -> {bf16 main, bf16 residual} fragment-packed ----------
// wpack frag index: (((vg*32 + ks)*2 + n)*2 + w) * 512 + lane*8 + j
// v = vg*32 + n*16 + (lane&15), k = ks*32 + (lane>>4)*8 + j
__global__ __launch_bounds__(256) void prep_w(const float* __restrict__ fcW,
                                              unsigned short* __restrict__ wpack) {
  int vg = blockIdx.x;  // 0..999
  for (int i = threadIdx.x; i < 32768; i += 256) {
    int ks = i >> 10;
    int n = (i >> 9) & 1;
    int lane = (i >> 3) & 63;
    int j = i & 7;
    int v = vg * 32 + n * 16 + (lane & 15);
    int k = ks * 32 + ((lane >> 4) << 3) + j;
    float f = fcW[(size_t)v * HH + k];
    unsigned short hb = f2bf(f);
    float e = f - bf2f(hb);
    size_t base = ((((size_t)vg * 32 + ks) * 2 + n) * 2) * 512 + (lane * 8 + j);
    wpack[base] = hb;
    wpack[base + 512] = f2bf(e);
  }
}

// ---------- init: h0 + seed token keys (tok = SOS = 1) ----------
__global__ __launch_bounds__(256) void init_kernel(const float* __restrict__ enc,
                                                   float* __restrict__ h4,
                                                   unsigned long long* __restrict__ gk0) {
  int i = blockIdx.x * 256 + threadIdx.x;  // 65536
  int b = i >> 10, u = i & 1023;
  h4[(((u >> 2) * NB + b) << 2) + (u & 3)] = enc[b * HH + u];
  if (i < NB) gk0[i * GKSTRIDE] = (unsigned long long)(0xFFFFFFFFu - 1u);  // tok 1
}

// ---------- GRU step (fp32) + embedding gather + key-buffer reset ----------
__global__ __launch_bounds__(256) void gru_kernel(
    const unsigned long long* __restrict__ gkin, unsigned long long* __restrict__ gkclr,
    const float* __restrict__ emb,
    const float* __restrict__ h4in, float* __restrict__ h4out,
    const float* __restrict__ Wih, const float* __restrict__ Whh,
    const float* __restrict__ bih, const float* __restrict__ bhh,
    unsigned short* __restrict__ ab, unsigned short* __restrict__ ae) {
  __shared__ float4 tile[2048];  // 32 KiB
  __shared__ int toks[NB];
  const int tid = threadIdx.x;
  const int lane = tid & 63;
  const int su = __builtin_amdgcn_readfirstlane(blockIdx.x * 4 + (tid >> 6));

  if (tid < NB) toks[tid] = (int)(0xFFFFFFFFu - (unsigned int)(gkin[tid * GKSTRIDE] & 0xFFFFFFFFu));
  if (blockIdx.x == 0 && tid < NB) gkclr[tid * GKSTRIDE] = 0ull;

  float air = 0.f, aiz = 0.f, ain = 0.f, ahr = 0.f, ahz = 0.f, ahn = 0.f;
  const float4* emb4 = (const float4*)emb;  // [VV][128]
  const float4* h4v = (const float4*)h4in;  // [256][64]

  // x part: gather emb rows; K=512 -> 4 chunks of 32 kq
  for (int c = 0; c < 4; ++c) {
    __syncthreads();
    for (int i = tid; i < 2048; i += 256)
      tile[i] = emb4[(size_t)toks[i & 63] * (EE / 4) + c * 32 + (i >> 6)];
    __syncthreads();
    const float* wr = Wih + (size_t)su * EE + c * 128;
    const float* wz = Wih + (size_t)(HH + su) * EE + c * 128;
    const float* wn = Wih + (size_t)(2 * HH + su) * EE + c * 128;
    for (int q = 0; q < 32; ++q) {
      float4 xv = tile[q * 64 + lane];
      float4 w0 = *(const float4*)(wr + q * 4);
      float4 w1 = *(const float4*)(wz + q * 4);
      float4 w2 = *(const float4*)(wn + q * 4);
      air += dot4(xv, w0);
      aiz += dot4(xv, w1);
      ain += dot4(xv, w2);
    }
  }
  // h part: K=1024 -> 8 chunks of 32 kq
  for (int c = 0; c < 8; ++c) {
    __syncthreads();
    for (int i = tid; i < 2048; i += 256) tile[i] = h4v[c * 2048 + i];
    __syncthreads();
    const float* wr = Whh + (size_t)su * HH + c * 128;
    const float* wz = Whh + (size_t)(HH + su) * HH + c * 128;
    const float* wn = Whh + (size_t)(2 * HH + su) * HH + c * 128;
    for (int q = 0; q < 32; ++q) {
      float4 hv = tile[q * 64 + lane];
      float4 w0 = *(const float4*)(wr + q * 4);
      float4 w1 = *(const float4*)(wz + q * 4);
      float4 w2 = *(const float4*)(wn + q * 4);
      ahr += dot4(hv, w0);
      ahz += dot4(hv, w1);
      ahn += dot4(hv, w2);
    }
  }

  float hold = h4in[(((su >> 2) * NB + lane) << 2) + (su & 3)];
  float r = sigmoidf_((air + bih[su]) + (ahr + bhh[su]));
  float z = sigmoidf_((aiz + bih[HH + su]) + (ahz + bhh[HH + su]));
  float n = tanhf((ain + bih[2 * HH + su]) + r * (ahn + bhh[2 * HH + su]));
  float hn = (1.0f - z) * n + z * hold;

  h4out[(((su >> 2) * NB + lane) << 2) + (su & 3)] = hn;
  // A-fragment layout: [m=b/16][ks=u/32][lane'=(b%16)+16*((u%32)/8)][j=u%8]
  int lp = (lane & 15) + (((su >> 3) & 3) << 4);
  size_t ai = ((((size_t)(lane >> 4) * 32 + (su >> 5)) * 64 + lp) << 3) + (su & 7);
  unsigned short hb = f2bf(hn);
  ab[ai] = hb;
  ae[ai] = f2bf(hn - bf2f(hb));
}

// ---------- FC: 4-term compensated bf16 MFMA -> raw logits into d_out + argmax atomic ---
// grid 1000 x 64thr; block vg covers 32 v (n=0,1), full K=1024
__global__ __launch_bounds__(64) void fc_kernel(const unsigned short* __restrict__ ab,
                                                const unsigned short* __restrict__ ae,
                                                const unsigned short* __restrict__ wpack,
                                                const float* __restrict__ fcb,
                                                float* __restrict__ out,
                                                unsigned long long* __restrict__ gk, int t) {
  const int lane = threadIdx.x;
  const int vg = blockIdx.x;  // 0..999
  f32x4 acc[4][2] = {};
  const short8* A = (const short8*)ab;
  const short8* Ae = (const short8*)ae;
  const short8* W = (const short8*)wpack + (size_t)vg * 32 * 4 * 64;

  for (int ks = 0; ks < 32; ++ks) {
    short8 hb[4], he[4], w[4];
#pragma unroll
    for (int m = 0; m < 4; ++m) {
      hb[m] = A[(m * 32 + ks) * 64 + lane];
      he[m] = Ae[(m * 32 + ks) * 64 + lane];
    }
#pragma unroll
    for (int q = 0; q < 4; ++q) w[q] = W[(ks * 4 + q) * 64 + lane];
#pragma unroll
    for (int n = 0; n < 2; ++n)
#pragma unroll
      for (int m = 0; m < 4; ++m) {
        acc[m][n] = __builtin_amdgcn_mfma_f32_16x16x32_bf16(hb[m], w[n * 2 + 0], acc[m][n], 0, 0, 0);
        acc[m][n] = __builtin_amdgcn_mfma_f32_16x16x32_bf16(he[m], w[n * 2 + 0], acc[m][n], 0, 0, 0);
        acc[m][n] = __builtin_amdgcn_mfma_f32_16x16x32_bf16(hb[m], w[n * 2 + 1], acc[m][n], 0, 0, 0);
        acc[m][n] = __builtin_amdgcn_mfma_f32_16x16x32_bf16(he[m], w[n * 2 + 1], acc[m][n], 0, 0, 0);
      }
  }

  const int r0 = (lane >> 4) << 2, c0 = lane & 15;
  const float bias0 = fcb[vg * 32 + c0];
  const float bias1 = fcb[vg * 32 + 16 + c0];
  unsigned long long kk[4][4];
#pragma unroll
  for (int m = 0; m < 4; ++m)
#pragma unroll
    for (int reg = 0; reg < 4; ++reg) {
      int b = m * 16 + r0 + reg;
      float v0 = acc[m][0][reg] + bias0;
      float v1 = acc[m][1][reg] + bias1;
      size_t ro = ((size_t)b * NSTEP + t) * VV + (size_t)vg * 32 + c0;
      out[ro] = v0;
      out[ro + 16] = v1;
      unsigned long long k0 =
          ((unsigned long long)ordkey(v0) << 32) | (unsigned long long)(0xFFFFFFFFu - (unsigned)(vg * 32 + c0));
      unsigned long long k1 =
          ((unsigned long long)ordkey(v1) << 32) | (unsigned long long)(0xFFFFFFFFu - (unsigned)(vg * 32 + 16 + c0));
      kk[m][reg] = k0 > k1 ? k0 : k1;
    }
#pragma unroll
  for (int d = 1; d < 16; d <<= 1)
#pragma unroll
    for (int m = 0; m < 4; ++m)
#pragma unroll
      for (int reg = 0; reg < 4; ++reg) {
        unsigned long long o = __shfl_xor(kk[m][reg], d, 64);
        if (o > kk[m][reg]) kk[m][reg] = o;
      }
  if (c0 == 0) {
#pragma unroll
    for (int m = 0; m < 4; ++m)
#pragma unroll
      for (int reg = 0; reg < 4; ++reg)
        atomicMax(&gk[(size_t)(m * 16 + r0 + reg) * GKSTRIDE], kk[m][reg]);
  }
}

// ---------- final: in-place log-softmax over each (b,t) row ----------
__global__ __launch_bounds__(256) void lsm_kernel(float* __restrict__ out) {
  const int bt = blockIdx.x;  // 0..2047, rows contiguous as [b][t]
  const int tid = threadIdx.x;
  float* row = out + (size_t)bt * VV;
  float4* r4 = (float4*)row;
  __shared__ float mred[256], sred[256];

  float m = -INFINITY, s = 0.f;
  for (int i = tid; i < VV / 4; i += 256) {
    float4 v = r4[i];
#pragma unroll
    for (int c = 0; c < 4; ++c) {
      float x = (&v.x)[c];
      if (x > m) {
        s = s * expf(m - x) + 1.0f;
        m = x;
      } else {
        s += expf(x - m);
      }
    }
  }
  mred[tid] = m;
  sred[tid] = s;
  __syncthreads();
  for (int off = 128; off > 0; off >>= 1) {
    if (tid < off) {
      float m1 = mred[tid], s1 = sred[tid];
      float m2 = mred[tid + off], s2 = sred[tid + off];
      float M = fmaxf(m1, m2);
      mred[tid] = M;
      sred[tid] = s1 * expf(m1 - M) + s2 * expf(m2 - M);
    }
    __syncthreads();
  }
  const float lse = mred[0] + logf(sred[0]);
  for (int i = tid; i < VV / 4; i += 256) {
    float4 v = r4[i];
    v.x -= lse; v.y -= lse; v.z -= lse; v.w -= lse;
    r4[i] = v;
  }
}

// ---------- hT tail ----------
__global__ __launch_bounds__(256) void final_kernel(const float* __restrict__ h4,
                                                    float* __restrict__ out) {
  int i = blockIdx.x * 256 + threadIdx.x;  // 65536
  int b = i >> 10, u = i & 1023;
  out[(size_t)NB * NSTEP * VV + i] = h4[(((u >> 2) * NB + b) << 2) + (u & 3)];
}

extern "C" void kernel_launch(void* const* d_in, const int* in_sizes, int n_in,
                              void* d_out, int out_size, void* d_ws, size_t ws_size,
                              hipStream_t stream) {
  const float* enc = (const float*)d_in[1];
  const float* emb = (const float*)d_in[2];
  const float* Wih = (const float*)d_in[3];
  const float* Whh = (const float*)d_in[4];
  const float* bih = (const float*)d_in[5];
  const float* bhh = (const float*)d_in[6];
  const float* fcW = (const float*)d_in[7];
  const float* fcb = (const float*)d_in[8];
  float* out = (float*)d_out;

  char* ws = (char*)d_ws;
  unsigned short* wpack = (unsigned short*)ws; ws += (size_t)1000 * 32 * 4 * 512 * 2;  // 131,072,000
  unsigned short* ab = (unsigned short*)ws; ws += (size_t)4 * 32 * 64 * 8 * 2;         // 131,072
  unsigned short* ae = (unsigned short*)ws; ws += (size_t)4 * 32 * 64 * 8 * 2;         // 131,072
  float* h4a = (float*)ws; ws += (size_t)NB * HH * 4;                                  // 262,144
  float* h4b = (float*)ws; ws += (size_t)NB * HH * 4;                                  // 262,144
  unsigned long long* gkA = (unsigned long long*)ws; ws += (size_t)NB * GKSTRIDE * 8;  // 262,144
  unsigned long long* gkB = (unsigned long long*)ws; ws += (size_t)NB * GKSTRIDE * 8;  // 262,144
  unsigned long long* gkbuf[2] = {gkA, gkB};

  prep_w<<<1000, 256, 0, stream>>>(fcW, wpack);
  init_kernel<<<256, 256, 0, stream>>>(enc, h4a, gkA);

  for (int t = 0; t < NSTEP; ++t) {
    float* hin = (t & 1) ? h4b : h4a;
    float* hout = (t & 1) ? h4a : h4b;
    // gru(t): reads token keys gk[t&1], zeroes gk[(t+1)&1] for fc(t)'s atomics
    gru_kernel<<<256, 256, 0, stream>>>(gkbuf[t & 1], gkbuf[(t + 1) & 1], emb, hin, hout,
                                        Wih, Whh, bih, bhh, ab, ae);
    fc_kernel<<<1000, 64, 0, stream>>>(ab, ae, wpack, fcb, out, gkbuf[(t + 1) & 1], t);
  }
  lsm_kernel<<<2048, 256, 0, stream>>>(out);
  final_kernel<<<256, 256, 0, stream>>>(h4a, out);  // t=31 wrote h4a
}

// Round 3
// 2830.254 us; speedup vs baseline: 1.6871x; 1.6580x over previous
//
#include <hip/hip_runtime.h>

#define VV 32000
#define EE 512
#define HH 1024
#define NB 64
#define NSTEP 32
#define GKSTRIDE 512

typedef __attribute__((ext_vector_type(8))) short short8;
typedef __attribute__((ext_vector_type(4))) float f32x4;
typedef unsigned long long u64;

#define MFMA16(a, b, c) __builtin_amdgcn_mfma_f32_16x16x32_bf16((a), (b), (c), 0, 0, 0)

__device__ __forceinline__ unsigned short f2bf(float f) {
  unsigned int u = __float_as_uint(f);
  u += 0x7fffu + ((u >> 16) & 1u);
  return (unsigned short)(u >> 16);
}
__device__ __forceinline__ float bf2f(unsigned short b) {
  return __uint_as_float(((unsigned int)b) << 16);
}
__device__ __forceinline__ float sigmoidf_(float x) { return 1.0f / (1.0f + expf(-x)); }
__device__ __forceinline__ unsigned int ordkey(float f) {
  unsigned int u = __float_as_uint(f);
  return u ^ ((u >> 31) ? 0xFFFFFFFFu : 0x80000000u);
}
__device__ __forceinline__ float ordkey_inv(unsigned int u) {
  return __uint_as_float((u & 0x80000000u) ? (u ^ 0x80000000u) : ~u);
}

// ---------- prep: [Wih | Whh] -> bf16 main+res fragments grouped by (ublock, gate) ----------
// wm/wr idx: (((ub*3+g)*48 + ks)*64 + lane)*8 + j ; row = g*1024 + ub*16 + (lane&15),
// k = ks*32 + (lane>>4)*8 + j ; k<512 -> Wih, else Whh[k-512]
__global__ __launch_bounds__(256) void prep_wcat(const float* __restrict__ Wih,
                                                 const float* __restrict__ Whh,
                                                 unsigned short* __restrict__ wm,
                                                 unsigned short* __restrict__ wr) {
  int ub = blockIdx.x / 3, g = blockIdx.x % 3;
  for (int e = threadIdx.x; e < 48 * 512; e += 256) {
    int ks = e >> 9, lane = (e >> 3) & 63, j = e & 7;
    int row = g * HH + ub * 16 + (lane & 15);
    int k = ks * 32 + ((lane >> 4) << 3) + j;
    float f = (k < EE) ? Wih[(size_t)row * EE + k] : Whh[(size_t)row * HH + (k - EE)];
    unsigned short m_ = f2bf(f);
    size_t idx = (((size_t)(ub * 3 + g) * 48 + ks) * 64 + lane) * 8 + j;
    wm[idx] = m_;
    wr[idx] = f2bf(f - bf2f(m_));
  }
}

// ---------- prep: fcW -> bf16 single fragments ----------
// idx: ((vg*32+ks)*2 + n)*512 + lane*8 + j ; v = vg*32 + n*16 + (lane&15)
__global__ __launch_bounds__(256) void prep_wfc(const float* __restrict__ fcW,
                                                unsigned short* __restrict__ wfc) {
  int vg = blockIdx.x;
  for (int e = threadIdx.x; e < 32768; e += 256) {
    int ks = e >> 10, n = (e >> 9) & 1, lane = (e >> 3) & 63, j = e & 7;
    int v = vg * 32 + n * 16 + (lane & 15);
    int k = ks * 32 + ((lane >> 4) << 3) + j;
    wfc[(((size_t)vg * 32 + ks) * 2 + n) * 512 + lane * 8 + j] = f2bf(fcW[(size_t)v * HH + k]);
  }
}

// ---------- init: h0 (row-major + frags), x0 = emb[SOS], clear gk ----------
__global__ __launch_bounds__(256) void init_kernel(
    const float* __restrict__ enc, const float* __restrict__ emb, float* __restrict__ h4a,
    unsigned short* __restrict__ ham, unsigned short* __restrict__ har,
    unsigned short* __restrict__ xam, unsigned short* __restrict__ xar,
    u64* __restrict__ gk) {
  int i = blockIdx.x * 256 + threadIdx.x;  // 65536
  int b = i >> 10, u = i & 1023;
  float hv = enc[i];
  h4a[i] = hv;
  unsigned short m_ = f2bf(hv);
  size_t idx = (((size_t)(b >> 4) * 32 + (u >> 5)) * 64 + ((b & 15) + (((u >> 3) & 3) << 4))) * 8 + (u & 7);
  ham[idx] = m_;
  har[idx] = f2bf(hv - bf2f(m_));
  if (i < NB * EE) {
    int b2 = i >> 9, k = i & 511;
    float xv = emb[EE + k];  // token SOS=1
    unsigned short xm = f2bf(xv);
    size_t xi = (((size_t)(b2 >> 4) * 16 + (k >> 5)) * 64 + ((b2 & 15) + (((k >> 3) & 3) << 4))) * 8 + (k & 7);
    xam[xi] = xm;
    xar[xi] = f2bf(xv - bf2f(xm));
  }
  if (i < NB) gk[(size_t)i * GKSTRIDE] = 0ull;
}

// ---------- GRU: gates via MFMA (K=1536 = x512 | h1024), fused nonlinearity ----------
// grid 256 = 64 ublocks x 4 mgroups; 4 waves split 48 ks
__global__ __launch_bounds__(256, 4) void gru_kernel(
    const unsigned short* __restrict__ xam, const unsigned short* __restrict__ xar,
    const unsigned short* __restrict__ him, const unsigned short* __restrict__ hir,
    const float* __restrict__ h4in, float* __restrict__ h4out,
    const unsigned short* __restrict__ wm, const unsigned short* __restrict__ wrs,
    const float* __restrict__ bih, const float* __restrict__ bhh,
    unsigned short* __restrict__ hom, unsigned short* __restrict__ hor) {
  __shared__ float red[4][16][65];
  const int tid = threadIdx.x, lane = tid & 63, w = tid >> 6;
  const int ub = blockIdx.x >> 2, mg = blockIdx.x & 3;
  f32x4 aR{}, aZ{}, aNX{}, aNH{};
  const short8* XM = (const short8*)xam;
  const short8* XR = (const short8*)xar;
  const short8* HM = (const short8*)him;
  const short8* HR = (const short8*)hir;
  const short8* WM = (const short8*)wm;
  const short8* WR = (const short8*)wrs;
#pragma unroll
  for (int s = 0; s < 12; ++s) {
    int ks = w * 12 + s;
    short8 am, ar;
    if (ks < 16) {
      int o = (mg * 16 + ks) * 64 + lane;
      am = XM[o]; ar = XR[o];
    } else {
      int o = (mg * 32 + (ks - 16)) * 64 + lane;
      am = HM[o]; ar = HR[o];
    }
    {
      int o = ((ub * 3 + 0) * 48 + ks) * 64 + lane;
      short8 wmv = WM[o], wrv = WR[o];
      aR = MFMA16(am, wmv, aR); aR = MFMA16(ar, wmv, aR); aR = MFMA16(am, wrv, aR);
    }
    {
      int o = ((ub * 3 + 1) * 48 + ks) * 64 + lane;
      short8 wmv = WM[o], wrv = WR[o];
      aZ = MFMA16(am, wmv, aZ); aZ = MFMA16(ar, wmv, aZ); aZ = MFMA16(am, wrv, aZ);
    }
    {
      int o = ((ub * 3 + 2) * 48 + ks) * 64 + lane;
      short8 wmv = WM[o], wrv = WR[o];
      if (ks < 16) {
        aNX = MFMA16(am, wmv, aNX); aNX = MFMA16(ar, wmv, aNX); aNX = MFMA16(am, wrv, aNX);
      } else {
        aNH = MFMA16(am, wmv, aNH); aNH = MFMA16(ar, wmv, aNH); aNH = MFMA16(am, wrv, aNH);
      }
    }
  }
#pragma unroll
  for (int reg = 0; reg < 4; ++reg) {
    int rr = ((lane >> 4) << 2) + reg, c = lane & 15;
    red[w][rr][c] = aR[reg];
    red[w][rr][16 + c] = aZ[reg];
    red[w][rr][32 + c] = aNX[reg];
    red[w][rr][48 + c] = aNH[reg];
  }
  __syncthreads();
  const int mrow = tid >> 4, uu = tid & 15;
  float R = 0.f, Z = 0.f, NX = 0.f, NH = 0.f;
#pragma unroll
  for (int q = 0; q < 4; ++q) {
    R += red[q][mrow][uu];
    Z += red[q][mrow][16 + uu];
    NX += red[q][mrow][32 + uu];
    NH += red[q][mrow][48 + uu];
  }
  const int b = mg * 16 + mrow, u = ub * 16 + uu;
  float r = sigmoidf_(R + bih[u] + bhh[u]);
  float z = sigmoidf_(Z + bih[HH + u] + bhh[HH + u]);
  float n = tanhf(NX + bih[2 * HH + u] + r * (NH + bhh[2 * HH + u]));
  float hold = h4in[b * HH + u];
  float hn = (1.0f - z) * n + z * hold;
  h4out[b * HH + u] = hn;
  unsigned short m_ = f2bf(hn);
  size_t idx = (((size_t)(b >> 4) * 32 + (u >> 5)) * 64 + ((b & 15) + (((u >> 3) & 3) << 4))) * 8 + (u & 7);
  hom[idx] = m_;
  hor[idx] = f2bf(hn - bf2f(m_));
}

// ---------- FC: logits via 2-term bf16 MFMA, 4 waves K-split, + approx argmax atomics ----------
__global__ __launch_bounds__(256, 4) void fc_kernel(
    const unsigned short* __restrict__ ham, const unsigned short* __restrict__ har,
    const unsigned short* __restrict__ wfc, const float* __restrict__ fcb,
    float* __restrict__ out, u64* __restrict__ gk, int t) {
  __shared__ float red[4][64][33];
  const int tid = threadIdx.x, lane = tid & 63, w = tid >> 6;
  const int vg = blockIdx.x;
  f32x4 acc[4][2] = {};
  const short8* HM = (const short8*)ham;
  const short8* HR = (const short8*)har;
  const short8* W = (const short8*)wfc;
#pragma unroll
  for (int s = 0; s < 8; ++s) {
    int ks = w * 8 + s;
    short8 am[4], ar[4], wv[2];
#pragma unroll
    for (int m = 0; m < 4; ++m) {
      int o = (m * 32 + ks) * 64 + lane;
      am[m] = HM[o]; ar[m] = HR[o];
    }
#pragma unroll
    for (int nt = 0; nt < 2; ++nt) wv[nt] = W[((vg * 32 + ks) * 2 + nt) * 64 + lane];
#pragma unroll
    for (int m = 0; m < 4; ++m)
#pragma unroll
      for (int nt = 0; nt < 2; ++nt) {
        acc[m][nt] = MFMA16(am[m], wv[nt], acc[m][nt]);
        acc[m][nt] = MFMA16(ar[m], wv[nt], acc[m][nt]);
      }
  }
#pragma unroll
  for (int m = 0; m < 4; ++m)
#pragma unroll
    for (int nt = 0; nt < 2; ++nt)
#pragma unroll
      for (int reg = 0; reg < 4; ++reg)
        red[w][m * 16 + ((lane >> 4) << 2) + reg][nt * 16 + (lane & 15)] = acc[m][nt][reg];
  __syncthreads();
  const int b = tid >> 2, c0 = (tid & 3) << 3;
  u64 best = 0;
  size_t ro = ((size_t)b * NSTEP + t) * VV + (size_t)vg * 32 + c0;
#pragma unroll
  for (int e = 0; e < 8; ++e) {
    int c = c0 + e;
    float v = red[0][b][c] + red[1][b][c] + red[2][b][c] + red[3][b][c] + fcb[vg * 32 + c];
    out[ro + e] = v;
    u64 key = ((u64)ordkey(v) << 32) | (u64)(0xFFFFFFFFu - (unsigned)(vg * 32 + c));
    if (key > best) best = key;
  }
  u64 o1 = __shfl_xor(best, 1, 64); if (o1 > best) best = o1;
  u64 o2 = __shfl_xor(best, 2, 64); if (o2 > best) best = o2;
  if ((tid & 3) == 0) atomicMax(&gk[(size_t)b * GKSTRIDE], best);
}

// ---------- select: exact-refined argmax + build next x-fragments + reset gk ----------
__global__ __launch_bounds__(256) void sel_kernel(
    const float* __restrict__ out, const float* __restrict__ fcW, const float* __restrict__ fcb,
    const float* __restrict__ emb, const float* __restrict__ h4,
    unsigned short* __restrict__ xam, unsigned short* __restrict__ xar,
    u64* __restrict__ gk, int t) {
  const int b = blockIdx.x, tid = threadIdx.x;
  __shared__ int scnt, stok;
  __shared__ int scand[32];
  __shared__ u64 skey[32];
  u64 key = gk[(size_t)b * GKSTRIDE];
  unsigned va = 0xFFFFFFFFu - (unsigned)(key & 0xFFFFFFFFu);
  float gmax = ordkey_inv((unsigned)(key >> 32));
  if (tid == 0) { scnt = 1; scand[0] = (int)va; }
  __syncthreads();
  const float thr = gmax - 0.06f;
  const float* row = out + ((size_t)b * NSTEP + t) * VV;
  for (int v = tid; v < VV; v += 256) {
    float x = row[v];
    if (x >= thr && v != (int)va) {
      int p = atomicAdd(&scnt, 1);
      if (p < 32) scand[p] = v;
    }
  }
  __syncthreads();
  int nc = scnt < 32 ? scnt : 32;
  const int w = tid >> 6, ln = tid & 63;
  for (int ci = w; ci < nc; ci += 4) {
    int v = scand[ci];
    float p = 0.f;
#pragma unroll
    for (int q = 0; q < 16; ++q) p += h4[b * HH + ln + (q << 6)] * fcW[(size_t)v * HH + ln + (q << 6)];
#pragma unroll
    for (int d = 1; d < 64; d <<= 1) p += __shfl_xor(p, d);
    if (ln == 0) skey[ci] = ((u64)ordkey(p + fcb[v]) << 32) | (u64)(0xFFFFFFFFu - (unsigned)v);
  }
  __syncthreads();
  if (tid == 0) {
    u64 bk = 0;
    for (int ci = 0; ci < nc; ++ci)
      if (skey[ci] > bk) bk = skey[ci];
    stok = (int)(0xFFFFFFFFu - (unsigned)(bk & 0xFFFFFFFFu));
  }
  __syncthreads();
  const int tok = stok;
  for (int k = tid; k < EE; k += 256) {
    float xv = emb[(size_t)tok * EE + k];
    unsigned short xm = f2bf(xv);
    size_t xi = (((size_t)(b >> 4) * 16 + (k >> 5)) * 64 + ((b & 15) + (((k >> 3) & 3) << 4))) * 8 + (k & 7);
    xam[xi] = xm;
    xar[xi] = f2bf(xv - bf2f(xm));
  }
  if (tid == 0) gk[(size_t)b * GKSTRIDE] = 0ull;
}

// ---------- final: in-place log-softmax per (b,t) row ----------
__global__ __launch_bounds__(256) void lsm_kernel(float* __restrict__ out) {
  const int bt = blockIdx.x;
  const int tid = threadIdx.x;
  float* row = out + (size_t)bt * VV;
  float4* r4 = (float4*)row;
  __shared__ float mred[256], sred[256];
  float m = -INFINITY, s = 0.f;
  for (int i = tid; i < VV / 4; i += 256) {
    float4 v = r4[i];
#pragma unroll
    for (int c = 0; c < 4; ++c) {
      float x = (&v.x)[c];
      if (x > m) { s = s * expf(m - x) + 1.0f; m = x; }
      else s += expf(x - m);
    }
  }
  mred[tid] = m; sred[tid] = s;
  __syncthreads();
  for (int off = 128; off > 0; off >>= 1) {
    if (tid < off) {
      float m1 = mred[tid], s1 = sred[tid];
      float m2 = mred[tid + off], s2 = sred[tid + off];
      float M = fmaxf(m1, m2);
      mred[tid] = M;
      sred[tid] = s1 * expf(m1 - M) + s2 * expf(m2 - M);
    }
    __syncthreads();
  }
  const float lse = mred[0] + logf(sred[0]);
  for (int i = tid; i < VV / 4; i += 256) {
    float4 v = r4[i];
    v.x -= lse; v.y -= lse; v.z -= lse; v.w -= lse;
    r4[i] = v;
  }
}

// ---------- hT tail ----------
__global__ __launch_bounds__(256) void final_kernel(const float* __restrict__ h4,
                                                    float* __restrict__ out) {
  int i = blockIdx.x * 256 + threadIdx.x;  // 65536
  out[(size_t)NB * NSTEP * VV + i] = h4[i];
}

extern "C" void kernel_launch(void* const* d_in, const int* in_sizes, int n_in,
                              void* d_out, int out_size, void* d_ws, size_t ws_size,
                              hipStream_t stream) {
  const float* enc = (const float*)d_in[1];
  const float* emb = (const float*)d_in[2];
  const float* Wih = (const float*)d_in[3];
  const float* Whh = (const float*)d_in[4];
  const float* bih = (const float*)d_in[5];
  const float* bhh = (const float*)d_in[6];
  const float* fcW = (const float*)d_in[7];
  const float* fcb = (const float*)d_in[8];
  float* out = (float*)d_out;

  char* ws = (char*)d_ws;
  unsigned short* wfc = (unsigned short*)ws; ws += (size_t)32768000 * 2;      // 65.5 MB
  unsigned short* wcm = (unsigned short*)ws; ws += (size_t)4718592 * 2;       // 9.44 MB
  unsigned short* wcr = (unsigned short*)ws; ws += (size_t)4718592 * 2;       // 9.44 MB
  unsigned short* hAm = (unsigned short*)ws; ws += (size_t)65536 * 2;
  unsigned short* hAr = (unsigned short*)ws; ws += (size_t)65536 * 2;
  unsigned short* hBm = (unsigned short*)ws; ws += (size_t)65536 * 2;
  unsigned short* hBr = (unsigned short*)ws; ws += (size_t)65536 * 2;
  unsigned short* xam = (unsigned short*)ws; ws += (size_t)32768 * 2;
  unsigned short* xar = (unsigned short*)ws; ws += (size_t)32768 * 2;
  float* h4a = (float*)ws; ws += (size_t)NB * HH * 4;
  float* h4b = (float*)ws; ws += (size_t)NB * HH * 4;
  u64* gk = (u64*)ws; ws += (size_t)NB * GKSTRIDE * 8;

  prep_wfc<<<1000, 256, 0, stream>>>(fcW, wfc);
  prep_wcat<<<192, 256, 0, stream>>>(Wih, Whh, wcm, wcr);
  init_kernel<<<256, 256, 0, stream>>>(enc, emb, h4a, hAm, hAr, xam, xar, gk);

  for (int t = 0; t < NSTEP; ++t) {
    const float* hin = (t & 1) ? h4b : h4a;
    float* hout = (t & 1) ? h4a : h4b;
    const unsigned short* him = (t & 1) ? hBm : hAm;
    const unsigned short* hir = (t & 1) ? hBr : hAr;
    unsigned short* hom = (t & 1) ? hAm : hBm;
    unsigned short* hor = (t & 1) ? hAr : hBr;
    gru_kernel<<<256, 256, 0, stream>>>(xam, xar, him, hir, hin, hout, wcm, wcr, bih, bhh, hom, hor);
    fc_kernel<<<1000, 256, 0, stream>>>(hom, hor, wfc, fcb, out, gk, t);
    sel_kernel<<<64, 256, 0, stream>>>(out, fcW, fcb, emb, hout, xam, xar, gk, t);
  }
  lsm_kernel<<<2048, 256, 0, stream>>>(out);
  final_kernel<<<256, 256, 0, stream>>>(h4a, out);  // t=31 wrote h4a
}

// Round 5
// 2735.481 us; speedup vs baseline: 1.7456x; 1.0346x over previous
//
#include <hip/hip_runtime.h>

#define VV 32000
#define EE 512
#define HH 1024
#define NB 64
#define NSTEP 32

typedef __attribute__((ext_vector_type(8))) short short8;
typedef __attribute__((ext_vector_type(4))) float f32x4;
typedef unsigned long long u64;

#define MFMA16(a, b, c) __builtin_amdgcn_mfma_f32_16x16x32_bf16((a), (b), (c), 0, 0, 0)

__device__ __forceinline__ unsigned short f2bf(float f) {
  unsigned int u = __float_as_uint(f);
  u += 0x7fffu + ((u >> 16) & 1u);
  return (unsigned short)(u >> 16);
}
__device__ __forceinline__ float bf2f(unsigned short b) {
  return __uint_as_float(((unsigned int)b) << 16);
}
__device__ __forceinline__ float sigmoidf_(float x) { return 1.0f / (1.0f + expf(-x)); }
__device__ __forceinline__ unsigned int ordkey(float f) {
  unsigned int u = __float_as_uint(f);
  return u ^ ((u >> 31) ? 0xFFFFFFFFu : 0x80000000u);
}
__device__ __forceinline__ float ordkey_inv(unsigned int u) {
  return __uint_as_float((u & 0x80000000u) ? (u ^ 0x80000000u) : ~u);
}

// ---------- prep: [Wih | Whh] -> bf16 main+res fragments grouped by (ublock, gate) ----------
__global__ __launch_bounds__(256) void prep_wcat(const float* __restrict__ Wih,
                                                 const float* __restrict__ Whh,
                                                 unsigned short* __restrict__ wm,
                                                 unsigned short* __restrict__ wr) {
  int ub = blockIdx.x / 3, g = blockIdx.x % 3;
  for (int e = threadIdx.x; e < 48 * 512; e += 256) {
    int ks = e >> 9, lane = (e >> 3) & 63, j = e & 7;
    int row = g * HH + ub * 16 + (lane & 15);
    int k = ks * 32 + ((lane >> 4) << 3) + j;
    float f = (k < EE) ? Wih[(size_t)row * EE + k] : Whh[(size_t)row * HH + (k - EE)];
    unsigned short m_ = f2bf(f);
    size_t idx = (((size_t)(ub * 3 + g) * 48 + ks) * 64 + lane) * 8 + j;
    wm[idx] = m_;
    wr[idx] = f2bf(f - bf2f(m_));
  }
}

// ---------- prep: fcW -> bf16 single fragments ----------
__global__ __launch_bounds__(256) void prep_wfc(const float* __restrict__ fcW,
                                                unsigned short* __restrict__ wfc) {
  int vg = blockIdx.x;
  for (int e = threadIdx.x; e < 32768; e += 256) {
    int ks = e >> 10, n = (e >> 9) & 1, lane = (e >> 3) & 63, j = e & 7;
    int v = vg * 32 + n * 16 + (lane & 15);
    int k = ks * 32 + ((lane >> 4) << 3) + j;
    wfc[(((size_t)vg * 32 + ks) * 2 + n) * 512 + lane * 8 + j] = f2bf(fcW[(size_t)v * HH + k]);
  }
}

// ---------- init: h0 (row-major + frags), x0 = emb[SOS] ----------
__global__ __launch_bounds__(256) void init_kernel(
    const float* __restrict__ enc, const float* __restrict__ emb, float* __restrict__ h4a,
    unsigned short* __restrict__ ham, unsigned short* __restrict__ har,
    unsigned short* __restrict__ xam, unsigned short* __restrict__ xar) {
  int i = blockIdx.x * 256 + threadIdx.x;  // 65536
  int b = i >> 10, u = i & 1023;
  float hv = enc[i];
  h4a[i] = hv;
  unsigned short m_ = f2bf(hv);
  size_t idx = (((size_t)(b >> 4) * 32 + (u >> 5)) * 64 + ((b & 15) + (((u >> 3) & 3) << 4))) * 8 + (u & 7);
  ham[idx] = m_;
  har[idx] = f2bf(hv - bf2f(m_));
  if (i < NB * EE) {
    int b2 = i >> 9, k = i & 511;
    float xv = emb[EE + k];  // token SOS=1
    unsigned short xm = f2bf(xv);
    size_t xi = (((size_t)(b2 >> 4) * 16 + (k >> 5)) * 64 + ((b2 & 15) + (((k >> 3) & 3) << 4))) * 8 + (k & 7);
    xam[xi] = xm;
    xar[xi] = f2bf(xv - bf2f(xm));
  }
}

// ---------- GRU: gates via MFMA (K=1536 = x512 | h1024), fused nonlinearity ----------
__global__ __launch_bounds__(256, 4) void gru_kernel(
    const unsigned short* __restrict__ xam, const unsigned short* __restrict__ xar,
    const unsigned short* __restrict__ him, const unsigned short* __restrict__ hir,
    const float* __restrict__ h4in, float* __restrict__ h4out,
    const unsigned short* __restrict__ wm, const unsigned short* __restrict__ wrs,
    const float* __restrict__ bih, const float* __restrict__ bhh,
    unsigned short* __restrict__ hom, unsigned short* __restrict__ hor) {
  __shared__ float red[4][16][65];
  const int tid = threadIdx.x, lane = tid & 63, w = tid >> 6;
  const int ub = blockIdx.x >> 2, mg = blockIdx.x & 3;
  f32x4 aR{}, aZ{}, aNX{}, aNH{};
  const short8* XM = (const short8*)xam;
  const short8* XR = (const short8*)xar;
  const short8* HM = (const short8*)him;
  const short8* HR = (const short8*)hir;
  const short8* WM = (const short8*)wm;
  const short8* WR = (const short8*)wrs;
#pragma unroll
  for (int s = 0; s < 12; ++s) {
    int ks = w * 12 + s;
    short8 am, ar;
    if (ks < 16) {
      int o = (mg * 16 + ks) * 64 + lane;
      am = XM[o]; ar = XR[o];
    } else {
      int o = (mg * 32 + (ks - 16)) * 64 + lane;
      am = HM[o]; ar = HR[o];
    }
    {
      int o = ((ub * 3 + 0) * 48 + ks) * 64 + lane;
      short8 wmv = WM[o], wrv = WR[o];
      aR = MFMA16(am, wmv, aR); aR = MFMA16(ar, wmv, aR); aR = MFMA16(am, wrv, aR);
    }
    {
      int o = ((ub * 3 + 1) * 48 + ks) * 64 + lane;
      short8 wmv = WM[o], wrv = WR[o];
      aZ = MFMA16(am, wmv, aZ); aZ = MFMA16(ar, wmv, aZ); aZ = MFMA16(am, wrv, aZ);
    }
    {
      int o = ((ub * 3 + 2) * 48 + ks) * 64 + lane;
      short8 wmv = WM[o], wrv = WR[o];
      if (ks < 16) {
        aNX = MFMA16(am, wmv, aNX); aNX = MFMA16(ar, wmv, aNX); aNX = MFMA16(am, wrv, aNX);
      } else {
        aNH = MFMA16(am, wmv, aNH); aNH = MFMA16(ar, wmv, aNH); aNH = MFMA16(am, wrv, aNH);
      }
    }
  }
#pragma unroll
  for (int reg = 0; reg < 4; ++reg) {
    int rr = ((lane >> 4) << 2) + reg, c = lane & 15;
    red[w][rr][c] = aR[reg];
    red[w][rr][16 + c] = aZ[reg];
    red[w][rr][32 + c] = aNX[reg];
    red[w][rr][48 + c] = aNH[reg];
  }
  __syncthreads();
  const int mrow = tid >> 4, uu = tid & 15;
  float R = 0.f, Z = 0.f, NX = 0.f, NH = 0.f;
#pragma unroll
  for (int q = 0; q < 4; ++q) {
    R += red[q][mrow][uu];
    Z += red[q][mrow][16 + uu];
    NX += red[q][mrow][32 + uu];
    NH += red[q][mrow][48 + uu];
  }
  const int b = mg * 16 + mrow, u = ub * 16 + uu;
  float r = sigmoidf_(R + bih[u] + bhh[u]);
  float z = sigmoidf_(Z + bih[HH + u] + bhh[HH + u]);
  float n = tanhf(NX + bih[2 * HH + u] + r * (NH + bhh[2 * HH + u]));
  float hold = h4in[b * HH + u];
  float hn = (1.0f - z) * n + z * hold;
  h4out[b * HH + u] = hn;
  unsigned short m_ = f2bf(hn);
  size_t idx = (((size_t)(b >> 4) * 32 + (u >> 5)) * 64 + ((b & 15) + (((u >> 3) & 3) << 4))) * 8 + (u & 7);
  hom[idx] = m_;
  hor[idx] = f2bf(hn - bf2f(m_));
}

// ---------- FC: 2-term bf16 MFMA (r3 numerics), atomic-free top-1 key per (b,vg) ----------
__global__ __launch_bounds__(256, 4) void fc_kernel(
    const unsigned short* __restrict__ ham, const unsigned short* __restrict__ har,
    const unsigned short* __restrict__ wfc, const float* __restrict__ fcb,
    float* __restrict__ out, u64* __restrict__ blkkeys, int t) {
  __shared__ float red[4][64][33];
  const int tid = threadIdx.x, lane = tid & 63, w = tid >> 6;
  const int vg = blockIdx.x;
  f32x4 acc[4][2] = {};
  const short8* HM = (const short8*)ham;
  const short8* HR = (const short8*)har;
  const short8* W = (const short8*)wfc;
#pragma unroll
  for (int s = 0; s < 8; ++s) {
    int ks = w * 8 + s;
    short8 am[4], ar[4], wv[2];
#pragma unroll
    for (int m = 0; m < 4; ++m) {
      int o = (m * 32 + ks) * 64 + lane;
      am[m] = HM[o]; ar[m] = HR[o];
    }
#pragma unroll
    for (int nt = 0; nt < 2; ++nt) wv[nt] = W[((vg * 32 + ks) * 2 + nt) * 64 + lane];
#pragma unroll
    for (int m = 0; m < 4; ++m)
#pragma unroll
      for (int nt = 0; nt < 2; ++nt) {
        acc[m][nt] = MFMA16(am[m], wv[nt], acc[m][nt]);
        acc[m][nt] = MFMA16(ar[m], wv[nt], acc[m][nt]);
      }
  }
#pragma unroll
  for (int m = 0; m < 4; ++m)
#pragma unroll
    for (int nt = 0; nt < 2; ++nt)
#pragma unroll
      for (int reg = 0; reg < 4; ++reg)
        red[w][m * 16 + ((lane >> 4) << 2) + reg][nt * 16 + (lane & 15)] = acc[m][nt][reg];
  __syncthreads();
  const int b = tid >> 2, c0 = (tid & 3) << 3;
  u64 k1 = 0;
  size_t ro = ((size_t)b * NSTEP + t) * VV + (size_t)vg * 32 + c0;
#pragma unroll
  for (int e = 0; e < 8; ++e) {
    int c = c0 + e;
    float v = red[0][b][c] + red[1][b][c] + red[2][b][c] + red[3][b][c] + fcb[vg * 32 + c];
    out[ro + e] = v;
    u64 key = ((u64)ordkey(v) << 32) | (u64)(0xFFFFFFFFu - (unsigned)(vg * 32 + c));
    if (key > k1) k1 = key;
  }
  {
    u64 o1 = __shfl_xor(k1, 1, 64);
    if (o1 > k1) k1 = o1;
    u64 o2 = __shfl_xor(k1, 2, 64);
    if (o2 > k1) k1 = o2;
  }
  if ((tid & 3) == 0) blkkeys[(size_t)b * 1000 + vg] = k1;
}

// ---------- select: key-max -> full-row candidate scan (r3 semantics) -> exact refine ----------
__global__ __launch_bounds__(256) void sel_kernel(
    const float* __restrict__ out, const u64* __restrict__ blkkeys,
    const float* __restrict__ fcW, const float* __restrict__ fcb,
    const float* __restrict__ emb, const float* __restrict__ h4,
    unsigned short* __restrict__ xam, unsigned short* __restrict__ xar, int t) {
  const int b = blockIdx.x, tid = threadIdx.x;
  __shared__ u64 skey[256];
  __shared__ int scnt, stok;
  __shared__ int scand[32];
  __shared__ u64 rkey[32];

  // Phase 0: approx global max from the 1000 per-block keys (4 KB)
  const u64* kb = blkkeys + (size_t)b * 1000;
  u64 mk = 0;
  for (int i = tid; i < 1000; i += 256) {
    u64 k = kb[i];
    if (k > mk) mk = k;
  }
  skey[tid] = mk;
  __syncthreads();
  for (int off = 128; off > 0; off >>= 1) {
    if (tid < off && skey[tid + off] > skey[tid]) skey[tid] = skey[tid + off];
    __syncthreads();
  }
  const u64 topkey = skey[0];
  const unsigned va = 0xFFFFFFFFu - (unsigned)(topkey & 0xFFFFFFFFu);
  const float Mf = ordkey_inv((unsigned)(topkey >> 32));
  if (tid == 0) { scnt = 1; scand[0] = (int)va; }
  __syncthreads();
  const float thr = Mf - 0.10f;

  // Phase 1: full-row candidate scan (proven r3 path; row is L2-hot)
  const float* row = out + ((size_t)b * NSTEP + t) * VV;
  for (int v = tid; v < VV; v += 256) {
    float x = row[v];
    if (x >= thr && v != (int)va) {
      int p = atomicAdd(&scnt, 1);
      if (p < 32) scand[p] = v;
    }
  }
  __syncthreads();
  int nc = scnt < 32 ? scnt : 32;

  // Phase 2: exact fp32 logits for candidates (one wave per candidate)
  const int w = tid >> 6, ln = tid & 63;
  for (int ci = w; ci < nc; ci += 4) {
    int v = scand[ci];
    float p = 0.f;
#pragma unroll
    for (int q = 0; q < 16; ++q)
      p += h4[b * HH + ln + (q << 6)] * fcW[(size_t)v * HH + ln + (q << 6)];
#pragma unroll
    for (int d = 1; d < 64; d <<= 1) p += __shfl_xor(p, d);
    if (ln == 0)
      rkey[ci] = ((u64)ordkey(p + fcb[v]) << 32) | (u64)(0xFFFFFFFFu - (unsigned)v);
  }
  __syncthreads();
  if (tid == 0) {
    u64 bk = 0;
    for (int ci = 0; ci < nc; ++ci)
      if (rkey[ci] > bk) bk = rkey[ci];
    stok = (int)(0xFFFFFFFFu - (unsigned)(bk & 0xFFFFFFFFu));
  }
  __syncthreads();

  // Phase 3: gather next-step x fragments
  const int tok = stok;
  for (int k = tid; k < EE; k += 256) {
    float xv = emb[(size_t)tok * EE + k];
    unsigned short xm = f2bf(xv);
    size_t xi = (((size_t)(b >> 4) * 16 + (k >> 5)) * 64 + ((b & 15) + (((k >> 3) & 3) << 4))) * 8 + (k & 7);
    xam[xi] = xm;
    xar[xi] = f2bf(xv - bf2f(xm));
  }
}

// ---------- final: in-place log-softmax per (b,t) row ----------
__global__ __launch_bounds__(256) void lsm_kernel(float* __restrict__ out) {
  const int bt = blockIdx.x;
  const int tid = threadIdx.x;
  float* row = out + (size_t)bt * VV;
  float4* r4 = (float4*)row;
  __shared__ float mred[256], sred[256];
  float m = -INFINITY, s = 0.f;
  for (int i = tid; i < VV / 4; i += 256) {
    float4 v = r4[i];
#pragma unroll
    for (int c = 0; c < 4; ++c) {
      float x = (&v.x)[c];
      if (x > m) { s = s * expf(m - x) + 1.0f; m = x; }
      else s += expf(x - m);
    }
  }
  mred[tid] = m; sred[tid] = s;
  __syncthreads();
  for (int off = 128; off > 0; off >>= 1) {
    if (tid < off) {
      float m1 = mred[tid], s1 = sred[tid];
      float m2 = mred[tid + off], s2 = sred[tid + off];
      float M = fmaxf(m1, m2);
      mred[tid] = M;
      sred[tid] = s1 * expf(m1 - M) + s2 * expf(m2 - M);
    }
    __syncthreads();
  }
  const float lse = mred[0] + logf(sred[0]);
  for (int i = tid; i < VV / 4; i += 256) {
    float4 v = r4[i];
    v.x -= lse; v.y -= lse; v.z -= lse; v.w -= lse;
    r4[i] = v;
  }
}

// ---------- hT tail ----------
__global__ __launch_bounds__(256) void final_kernel(const float* __restrict__ h4,
                                                    float* __restrict__ out) {
  int i = blockIdx.x * 256 + threadIdx.x;  // 65536
  out[(size_t)NB * NSTEP * VV + i] = h4[i];
}

extern "C" void kernel_launch(void* const* d_in, const int* in_sizes, int n_in,
                              void* d_out, int out_size, void* d_ws, size_t ws_size,
                              hipStream_t stream) {
  const float* enc = (const float*)d_in[1];
  const float* emb = (const float*)d_in[2];
  const float* Wih = (const float*)d_in[3];
  const float* Whh = (const float*)d_in[4];
  const float* bih = (const float*)d_in[5];
  const float* bhh = (const float*)d_in[6];
  const float* fcW = (const float*)d_in[7];
  const float* fcb = (const float*)d_in[8];
  float* out = (float*)d_out;

  char* ws = (char*)d_ws;
  unsigned short* wfc = (unsigned short*)ws; ws += (size_t)32768000 * 2;  // 65.5 MB
  unsigned short* wcm = (unsigned short*)ws; ws += (size_t)4718592 * 2;   // 9.44 MB
  unsigned short* wcr = (unsigned short*)ws; ws += (size_t)4718592 * 2;   // 9.44 MB
  unsigned short* hAm = (unsigned short*)ws; ws += (size_t)65536 * 2;
  unsigned short* hAr = (unsigned short*)ws; ws += (size_t)65536 * 2;
  unsigned short* hBm = (unsigned short*)ws; ws += (size_t)65536 * 2;
  unsigned short* hBr = (unsigned short*)ws; ws += (size_t)65536 * 2;
  unsigned short* xam = (unsigned short*)ws; ws += (size_t)32768 * 2;
  unsigned short* xar = (unsigned short*)ws; ws += (size_t)32768 * 2;
  float* h4a = (float*)ws; ws += (size_t)NB * HH * 4;
  float* h4b = (float*)ws; ws += (size_t)NB * HH * 4;
  u64* blkkeys = (u64*)ws; ws += (size_t)NB * 1000 * 8;  // 512 KB

  prep_wfc<<<1000, 256, 0, stream>>>(fcW, wfc);
  prep_wcat<<<192, 256, 0, stream>>>(Wih, Whh, wcm, wcr);
  init_kernel<<<256, 256, 0, stream>>>(enc, emb, h4a, hAm, hAr, xam, xar);

  for (int t = 0; t < NSTEP; ++t) {
    const float* hin = (t & 1) ? h4b : h4a;
    float* hout = (t & 1) ? h4a : h4b;
    const unsigned short* him = (t & 1) ? hBm : hAm;
    const unsigned short* hir = (t & 1) ? hBr : hAr;
    unsigned short* hom = (t & 1) ? hAm : hBm;
    unsigned short* hor = (t & 1) ? hAr : hBr;
    gru_kernel<<<256, 256, 0, stream>>>(xam, xar, him, hir, hin, hout, wcm, wcr, bih, bhh, hom, hor);
    fc_kernel<<<1000, 256, 0, stream>>>(hom, hor, wfc, fcb, out, blkkeys, t);
    sel_kernel<<<64, 256, 0, stream>>>(out, blkkeys, fcW, fcb, emb, hout, xam, xar, t);
  }
  lsm_kernel<<<2048, 256, 0, stream>>>(out);
  final_kernel<<<256, 256, 0, stream>>>(h4a, out);  // t=31 wrote h4a
}